// Round 11
// baseline (189.374 us; speedup 1.0000x reference)
//
#include <hip/hip_runtime.h>
#include <hip/hip_bf16.h>

typedef __attribute__((ext_vector_type(8))) short bf16x8;
typedef __attribute__((ext_vector_type(4))) float f32x4;
typedef __attribute__((ext_vector_type(2))) unsigned u32x2;

#define LOG2E  1.4426950408889634f
#define QSCALE 0.08838834764831845f   // 1/sqrt(128)
#define DMTHR  8.0f                   // defer-max threshold (ln domain)

// native packed fp32->bf16 RNE convert (no builtin on gfx950; register-pure asm)
__device__ __forceinline__ unsigned cvt_pk_bf16(float lo, float hi) {
  unsigned r;
  asm("v_cvt_pk_bf16_f32 %0, %1, %2" : "=v"(r) : "v"(lo), "v"(hi));
  return r;
}

// Block = 64 q-rows, 4 waves. Waves 0-1 (team 0): kv-half 0; waves 2-3
// (team 1): kv-half 1. K/V single-buffered per team (KVBLK=32), staged
// COOPERATIVELY by all 256 threads (both teams' tiles = one 64-row job).
// Partial softmax states merged through LDS at the end. 33 KB LDS.
__global__ __launch_bounds__(256, 2) void attn_fwd(
    const float* __restrict__ Qg, const float* __restrict__ Kg,
    const float* __restrict__ Vg, float* __restrict__ Og)
{
  __shared__ short Ksm[2][32 * 128];   // [team][kv][d]  2 x 8 KB
  __shared__ short Vsm[2][128 * 32];   // [team][d][kv]  2 x 8 KB
  __shared__ float MLsm[2][2][2][16];  // [pair][m|l][mt][lo]

  const int tid  = threadIdx.x;
  const int lane = tid & 63;
  const int wave = tid >> 6;      // 0..3
  const int team = wave >> 1;     // kv-split half
  const int rh   = wave & 1;      // row half within block (pair id)
  const int g    = lane >> 4;     // 0..3
  const int lo   = lane & 15;     // 0..15
  const int lo7  = lo & 7;
  const int lo3  = lo & 3;

  const int bh = blockIdx.x;            // head fastest
  const int gq = 31 - blockIdx.y;       // heavy blocks dispatched first
  const int q0 = gq * 64;
  const int h  = gq + 1;                // KVBLK=32 tiles per team

  const size_t base = (size_t)bh * 2048 * 128;
  const float* Qb = Qg + base;
  const float* Kb = Kg + base;
  const float* Vb = Vg + base;
  float*       Ob = Og + base;

  // cooperative staging index helpers (cross-team!)
  const int vd32 = tid & 31;     // V: d within 32-group
  const int vq8  = tid >> 5;     // V: logical quad base 0..7

  // --- Q fragments (scaled). B-frag role for swapped QK^T: col=lo, k=g*8+j ---
  bf16x8 qf[2][4];
  #pragma unroll
  for (int mt = 0; mt < 2; ++mt) {
    const int row = q0 + rh * 32 + mt * 16 + lo;
    const float* qr = Qb + (size_t)row * 128 + g * 8;
    #pragma unroll
    for (int kb = 0; kb < 4; ++kb) {
      f32x4 a = *(const f32x4*)(qr + kb * 32);
      f32x4 b = *(const f32x4*)(qr + kb * 32 + 4);
      union { bf16x8 v; unsigned u[4]; } w;
      w.u[0] = cvt_pk_bf16(a[0] * QSCALE, a[1] * QSCALE);
      w.u[1] = cvt_pk_bf16(a[2] * QSCALE, a[3] * QSCALE);
      w.u[2] = cvt_pk_bf16(b[0] * QSCALE, b[1] * QSCALE);
      w.u[3] = cvt_pk_bf16(b[2] * QSCALE, b[3] * QSCALE);
      qf[mt][kb] = w.v;
    }
  }

  float m_st[2] = {-3.0e38f, -3.0e38f};
  float l_st[2] = {0.0f, 0.0f};
  f32x4 o_acc[2][8];   // O^T: col=q(lo), row d = nd*16 + g*4 + r
  #pragma unroll
  for (int mt = 0; mt < 2; ++mt)
    #pragma unroll
    for (int nd = 0; nd < 8; ++nd) o_acc[mt][nd] = (f32x4){0.f, 0.f, 0.f, 0.f};

  const bool b1 = (g >> 1) & 1;
  const bool b0 = g & 1;

  // prefetch registers (64 floats, matching R6's clean 128-VGPR profile)
  f32x4 kpa[4], kpb[4];     // K: 4 chunks x 8 floats
  float vpf[2][4][4];       // V: [i2][jj][e]

  // ---- cooperative load+write of both teams' tile `it` (it in tile units) ----
  // K: 1024 chunks; lr=idx>>4 in 0..63; t=lr>>5; kr=lr&31
  // V: logical quad lq = vq8 + 8*i2 in 0..15; t=lq>>3; q4=lq&7
  #define STAGE_LOAD(it)                                                        \
    {                                                                           \
      const int tb = (it) * 32;                                                 \
      _Pragma("unroll")                                                         \
      for (int ii = 0; ii < 4; ++ii) {                                          \
        const int idx = ii * 256 + tid;                                         \
        const int lr = idx >> 4, dc16 = idx & 15;                               \
        const int t = lr >> 5, kr = lr & 31;                                    \
        const float* src = Kb + (size_t)(t * 32 * h + tb + kr) * 128 + dc16 * 8;\
        kpa[ii] = *(const f32x4*)src;                                           \
        kpb[ii] = *(const f32x4*)(src + 4);                                     \
      }                                                                         \
      _Pragma("unroll")                                                         \
      for (int i2 = 0; i2 < 2; ++i2) {                                          \
        const int lq = vq8 + 8 * i2;                                            \
        const int t = lq >> 3, q4 = lq & 7;                                     \
        _Pragma("unroll")                                                       \
        for (int jj = 0; jj < 4; ++jj) {                                        \
          const int row = vd32 + jj * 32;                                       \
          const float* v0 = Vb + (size_t)(t * 32 * h + tb + 4 * q4) * 128 + row;\
          _Pragma("unroll")                                                     \
          for (int e = 0; e < 4; ++e) vpf[i2][jj][e] = v0[(size_t)e * 128];     \
        }                                                                       \
      }                                                                         \
    }

  #define STAGE_WRITE()                                                         \
    {                                                                           \
      _Pragma("unroll")                                                         \
      for (int ii = 0; ii < 4; ++ii) {                                          \
        const int idx = ii * 256 + tid;                                         \
        const int lr = idx >> 4, dc16 = idx & 15;                               \
        const int t = lr >> 5, kr = lr & 31;                                    \
        union { bf16x8 v; unsigned u[4]; } w;                                   \
        w.u[0] = cvt_pk_bf16(kpa[ii][0], kpa[ii][1]);                           \
        w.u[1] = cvt_pk_bf16(kpa[ii][2], kpa[ii][3]);                           \
        w.u[2] = cvt_pk_bf16(kpb[ii][0], kpb[ii][1]);                           \
        w.u[3] = cvt_pk_bf16(kpb[ii][2], kpb[ii][3]);                           \
        *(bf16x8*)&Ksm[t][kr * 128 + ((dc16 ^ (kr & 7)) * 8)] = w.v;            \
      }                                                                         \
      _Pragma("unroll")                                                         \
      for (int i2 = 0; i2 < 2; ++i2) {                                          \
        const int lq = vq8 + 8 * i2;                                            \
        const int t = lq >> 3, q4 = lq & 7;                                     \
        _Pragma("unroll")                                                       \
        for (int jj = 0; jj < 4; ++jj) {                                        \
          const int row = vd32 + jj * 32;                                       \
          const unsigned u0 = cvt_pk_bf16(vpf[i2][jj][0], vpf[i2][jj][1]);      \
          const unsigned u1 = cvt_pk_bf16(vpf[i2][jj][2], vpf[i2][jj][3]);      \
          *(u32x2*)&Vsm[t][row * 32 + (((q4 >> 1) ^ (row & 3)) * 8)             \
                           + (q4 & 1) * 4] = (u32x2){u0, u1};                   \
        }                                                                       \
      }                                                                         \
    }

  // ---- prologue: stage tile 0 of both teams ----
  STAGE_LOAD(0)
  STAGE_WRITE()
  __syncthreads();

  const int kvbase = team * 32 * h;
  const int rowmax = q0 + rh * 32 + 31;

  for (int i = 0; i < h; ++i) {
    const int kv0 = kvbase + 32 * i;
    const bool have_next = (i + 1 < h);

    // ---- issue next-tile loads NOW; latency hides under compute ----
    if (have_next) STAGE_LOAD(i + 1)
    __builtin_amdgcn_sched_barrier(0);   // pin load issue above compute

    if (kv0 <= rowmax) {   // wave has unmasked work in this tile
      // ---- swapped QK^T: S^T = mfma(K, Q); lane: S[q=lo][kv=nb*16+g*4+r] ----
      f32x4 s[2][2];
      #pragma unroll
      for (int mt = 0; mt < 2; ++mt)
        #pragma unroll
        for (int nb = 0; nb < 2; ++nb) s[mt][nb] = (f32x4){0.f, 0.f, 0.f, 0.f};

      __builtin_amdgcn_s_setprio(1);
      #pragma unroll
      for (int nb = 0; nb < 2; ++nb) {
        #pragma unroll
        for (int kb = 0; kb < 4; ++kb) {
          bf16x8 kf = *(const bf16x8*)&Ksm[team][(nb * 16 + lo) * 128 + (((kb * 4 + g) ^ lo7) * 8)];
          s[0][nb] = __builtin_amdgcn_mfma_f32_16x16x32_bf16(kf, qf[0][kb], s[0][nb], 0, 0, 0);
          s[1][nb] = __builtin_amdgcn_mfma_f32_16x16x32_bf16(kf, qf[1][kb], s[1][nb], 0, 0, 0);
        }
      }
      __builtin_amdgcn_s_setprio(0);

      // ---- causal mask (only tiles touching the diagonal) ----
      if (kv0 + 31 > q0 + rh * 32) {
        #pragma unroll
        for (int mt = 0; mt < 2; ++mt) {
          const int qrow = q0 + rh * 32 + mt * 16 + lo;
          #pragma unroll
          for (int nb = 0; nb < 2; ++nb) {
            const int kvb = kv0 + nb * 16 + g * 4;
            #pragma unroll
            for (int r = 0; r < 4; ++r)
              if (kvb + r > qrow) s[mt][nb][r] = -1.0e30f;
          }
        }
      }

      // ---- online softmax (scalar per lane, defer-max) + P -> B-frag ----
      bf16x8 pfrag[2];
      #pragma unroll
      for (int mt = 0; mt < 2; ++mt) {
        float tm = s[mt][0][0];
        #pragma unroll
        for (int nb = 0; nb < 2; ++nb)
          #pragma unroll
          for (int r = 0; r < 4; ++r) tm = fmaxf(tm, s[mt][nb][r]);
        tm = fmaxf(tm, __shfl_xor(tm, 16));
        tm = fmaxf(tm, __shfl_xor(tm, 32));

        if (!__all(tm <= m_st[mt] + DMTHR)) {
          const float mn = fmaxf(m_st[mt], tm);
          const float alpha = __builtin_amdgcn_exp2f((m_st[mt] - mn) * LOG2E);
          m_st[mt] = mn;
          l_st[mt] *= alpha;
          #pragma unroll
          for (int nd = 0; nd < 8; ++nd)
            #pragma unroll
            for (int r = 0; r < 4; ++r) o_acc[mt][nd][r] *= alpha;
        }

        float p[2][4];
        float ps = 0.0f;
        #pragma unroll
        for (int nb = 0; nb < 2; ++nb)
          #pragma unroll
          for (int r = 0; r < 4; ++r) {
            p[nb][r] = __builtin_amdgcn_exp2f((s[mt][nb][r] - m_st[mt]) * LOG2E);
            ps += p[nb][r];
          }
        ps += __shfl_xor(ps, 16);
        ps += __shfl_xor(ps, 32);
        l_st[mt] += ps;

        // pack P pairs: pk[n0][w] = kv pair (n0*16 + g*4 + 2w, +1), q=lo
        unsigned pk[2][2];
        #pragma unroll
        for (int n0 = 0; n0 < 2; ++n0)
          #pragma unroll
          for (int w = 0; w < 2; ++w)
            pk[n0][w] = cvt_pk_bf16(p[n0][2 * w], p[n0][2 * w + 1]);

        // butterfly: reg-bit n0 <-> lane-bit b1 (xor32), then rb <-> b0 (xor16)
        unsigned q2[2][2];
        #pragma unroll
        for (int w = 0; w < 2; ++w) {
          unsigned a = pk[0][w], b = pk[1][w];
          unsigned recv = __shfl_xor(b1 ? a : b, 32);
          unsigned r0 = b1 ? recv : a;
          unsigned r1 = b1 ? b : recv;
          unsigned recv2 = __shfl_xor(b0 ? r0 : r1, 16);
          q2[0][w] = b0 ? recv2 : r0;
          q2[1][w] = b0 ? r1 : recv2;
        }
        union { bf16x8 v; unsigned u[4]; } fb;
        fb.u[0] = q2[0][0]; fb.u[1] = q2[0][1]; fb.u[2] = q2[1][0]; fb.u[3] = q2[1][1];
        pfrag[mt] = fb.v;   // B-frag: P^T[kv = g*8 + j][q = lo]
      }

      // ---- PV: O^T += mfma(A=V^T, B=P^T), K-dim = 32 ----
      __builtin_amdgcn_s_setprio(1);
      #pragma unroll
      for (int nd = 0; nd < 8; ++nd) {
        const int vrow = nd * 16 + lo;
        bf16x8 vf = *(const bf16x8*)&Vsm[team][vrow * 32 + ((g ^ lo3) * 8)];
        o_acc[0][nd] = __builtin_amdgcn_mfma_f32_16x16x32_bf16(vf, pfrag[0], o_acc[0][nd], 0, 0, 0);
        o_acc[1][nd] = __builtin_amdgcn_mfma_f32_16x16x32_bf16(vf, pfrag[1], o_acc[1][nd], 0, 0, 0);
      }
      __builtin_amdgcn_s_setprio(0);
    }

    __syncthreads();   // barrier1: all waves done reading tile i

    // ---- write prefetched regs -> both team buffers (vmcnt drains here) ----
    if (have_next) STAGE_WRITE()
    __syncthreads();   // barrier2: tile i+1 published
  }

  // ---- merge kv-split halves: pair = waves (rh, rh+2) on same q-rows ----
  float* Opart = (rh == 0) ? (float*)Ksm : (float*)Vsm;   // 32x128 f32 per pair

  if (team == 1) {
    #pragma unroll
    for (int mt = 0; mt < 2; ++mt) {
      #pragma unroll
      for (int nd = 0; nd < 8; ++nd)
        *(f32x4*)&Opart[(mt * 16 + lo) * 128 + nd * 16 + g * 4] = o_acc[mt][nd];
      if (g == 0) {
        MLsm[rh][0][mt][lo] = m_st[mt];
        MLsm[rh][1][mt][lo] = l_st[mt];
      }
    }
  }
  __syncthreads();

  if (team == 0) {
    #pragma unroll
    for (int mt = 0; mt < 2; ++mt) {
      const float mB = MLsm[rh][0][mt][lo];
      const float lB = MLsm[rh][1][mt][lo];
      const float m  = fmaxf(m_st[mt], mB);
      const float aA = __builtin_amdgcn_exp2f((m_st[mt] - m) * LOG2E);
      const float aB = __builtin_amdgcn_exp2f((mB - m) * LOG2E);
      const float l  = l_st[mt] * aA + lB * aB;
      const float inv = 1.0f / l;
      const int q = q0 + rh * 32 + mt * 16 + lo;
      #pragma unroll
      for (int nd = 0; nd < 8; ++nd) {
        f32x4 oB = *(const f32x4*)&Opart[(mt * 16 + lo) * 128 + nd * 16 + g * 4];
        f32x4 o;
        #pragma unroll
        for (int r = 0; r < 4; ++r)
          o[r] = (o_acc[mt][nd][r] * aA + oB[r] * aB) * inv;
        *(f32x4*)(Ob + (size_t)q * 128 + nd * 16 + g * 4) = o;
      }
    }
  }
}

extern "C" void kernel_launch(void* const* d_in, const int* in_sizes, int n_in,
                              void* d_out, int out_size, void* d_ws, size_t ws_size,
                              hipStream_t stream) {
  const float* Q = (const float*)d_in[0];
  const float* K = (const float*)d_in[1];
  const float* V = (const float*)d_in[2];
  float* O = (float*)d_out;
  // 64 heads x 32 row-groups of 64 q-rows; heavy groups first. 2048 blocks
  // -> ~8/CU queued: dynamic backfill smooths causal imbalance; short kv
  // chains (<=32 half-tiles) per block.
  attn_fwd<<<dim3(64, 32), 256, 0, stream>>>(Q, K, V, O);
}

// Round 14
// 174.744 us; speedup vs baseline: 1.0837x; 1.0837x over previous
//
#include <hip/hip_runtime.h>
#include <hip/hip_bf16.h>

typedef __attribute__((ext_vector_type(8))) short bf16x8;
typedef __attribute__((ext_vector_type(4))) float f32x4;

#define LOG2E  1.4426950408889634f
#define QSCALE 0.08838834764831845f   // 1/sqrt(128)
#define DMTHR  8.0f                   // defer-max threshold (ln domain)

// native packed fp32->bf16 RNE convert (no builtin on gfx950; register-pure asm)
__device__ __forceinline__ unsigned cvt_pk_bf16(float lo, float hi) {
  unsigned r;
  asm("v_cvt_pk_bf16_f32 %0, %1, %2" : "=v"(r) : "v"(lo), "v"(hi));
  return r;
}

// Block = 128 q-rows, 8 waves. Waves 0-3 (team 0): first half of causal KV
// range; waves 4-7 (team 1): second half. Same q-rows; partial softmax
// states merged through LDS at the end. K/V single-buffered per team,
// staged cooperatively by all 512 threads. 66 KB LDS -> 2 blocks/CU,
// 16 waves/CU; per-block chain halves to <=16 iterations.
__global__ __launch_bounds__(512, 2) void attn_fwd(
    const float* __restrict__ Qg, const float* __restrict__ Kg,
    const float* __restrict__ Vg, float* __restrict__ Og)
{
  __shared__ short Ksm[2][64 * 128];    // [team][kv][d]  2 x 16 KB
  __shared__ short Vsm[2][128 * 64];    // [team][d][kv]  2 x 16 KB
  __shared__ float MLsm[4][2][2][16];   // [pair][m|l][mt][lo]  1 KB

  const int tid  = threadIdx.x;
  const int lane = tid & 63;
  const int wave = tid >> 6;      // 0..7
  const int team = wave >> 2;     // kv-half
  const int wv   = wave & 3;      // row group (32 rows each)
  const int g    = lane >> 4;     // 0..3
  const int lo   = lane & 15;     // 0..15
  const int lo7  = lo & 7;

  const int bh = blockIdx.x;            // head fastest
  const int qt = 15 - blockIdx.y;       // heavy blocks dispatched first
  const int q0 = qt * 128;
  const int h  = qt + 1;                // iterations per team (64-wide tiles)

  const size_t base = (size_t)bh * 2048 * 128;
  const float* Qb = Qg + base;
  const float* Kb = Kg + base;
  const float* Vb = Vg + base;
  float*       Ob = Og + base;

  // cooperative staging index helpers (cover BOTH teams)
  const int vd   = tid & 31;     // V: d within 32-group
  const int vq   = tid >> 5;     // V: 0..15 -> lteam = vq>>3, vprb = vq&7

  // --- Q fragments (scaled). B-frag role for swapped QK^T: col=lo, k=g*8+j ---
  bf16x8 qf[2][4];
  #pragma unroll
  for (int mt = 0; mt < 2; ++mt) {
    const int row = q0 + wv * 32 + mt * 16 + lo;
    const float* qr = Qb + (size_t)row * 128 + g * 8;
    #pragma unroll
    for (int kb = 0; kb < 4; ++kb) {
      f32x4 a = *(const f32x4*)(qr + kb * 32);
      f32x4 b = *(const f32x4*)(qr + kb * 32 + 4);
      union { bf16x8 v; unsigned u[4]; } w;
      w.u[0] = cvt_pk_bf16(a[0] * QSCALE, a[1] * QSCALE);
      w.u[1] = cvt_pk_bf16(a[2] * QSCALE, a[3] * QSCALE);
      w.u[2] = cvt_pk_bf16(b[0] * QSCALE, b[1] * QSCALE);
      w.u[3] = cvt_pk_bf16(b[2] * QSCALE, b[3] * QSCALE);
      qf[mt][kb] = w.v;
    }
  }

  float m_st[2] = {-3.0e38f, -3.0e38f};
  float l_st[2] = {0.0f, 0.0f};
  f32x4 o_acc[2][8];   // O^T: col=q(lo), row d = nd*16 + g*4 + r
  #pragma unroll
  for (int mt = 0; mt < 2; ++mt)
    #pragma unroll
    for (int nd = 0; nd < 8; ++nd) o_acc[mt][nd] = (f32x4){0.f, 0.f, 0.f, 0.f};

  const bool b1 = (g >> 1) & 1;
  const bool b0 = g & 1;

  // prefetch registers (same per-thread volume as the verified R6 kernel)
  f32x4 kpa[4], kpb[4];     // K: 4 chunks x 8 floats (both teams interleaved)
  float vp[4][4][2];        // V: [i][jj][pair]

  // K: idx = ii*512+tid in [0,2048); lteam = idx>>10; kr = (idx&1023)>>4;
  //    dc16 = idx&15; src kv = lteam*h*64 + tile*64 + kr
  // V: lteam = vq>>3; pr = (vq&7) + ii*8 in [0,32) kv-pairs
  #define STAGE_LOAD(it)                                                        \
    {                                                                           \
      _Pragma("unroll")                                                         \
      for (int ii = 0; ii < 4; ++ii) {                                          \
        const int idx = ii * 512 + tid;                                         \
        const int lteam = idx >> 10, w1 = idx & 1023;                           \
        const int kr = w1 >> 4, dc16 = w1 & 15;                                 \
        const float* src =                                                      \
            Kb + (size_t)(lteam * h * 64 + (it) * 64 + kr) * 128 + dc16 * 8;    \
        kpa[ii] = *(const f32x4*)src;                                           \
        kpb[ii] = *(const f32x4*)(src + 4);                                     \
      }                                                                         \
      {                                                                         \
        const int lteam = vq >> 3, vprb = vq & 7;                               \
        _Pragma("unroll")                                                       \
        for (int ii = 0; ii < 4; ++ii) {                                        \
          const int pr = vprb + ii * 8;                                         \
          const float* v0 =                                                     \
              Vb + (size_t)(lteam * h * 64 + (it) * 64 + 2 * pr) * 128 + vd;    \
          _Pragma("unroll")                                                     \
          for (int jj = 0; jj < 4; ++jj) {                                      \
            vp[ii][jj][0] = v0[jj * 32];                                        \
            vp[ii][jj][1] = v0[jj * 32 + 128];                                  \
          }                                                                     \
        }                                                                       \
      }                                                                         \
    }

  #define STAGE_WRITE()                                                         \
    {                                                                           \
      _Pragma("unroll")                                                         \
      for (int ii = 0; ii < 4; ++ii) {                                          \
        const int idx = ii * 512 + tid;                                         \
        const int lteam = idx >> 10, w1 = idx & 1023;                           \
        const int kr = w1 >> 4, dc16 = w1 & 15;                                 \
        union { bf16x8 v; unsigned u[4]; } w;                                   \
        w.u[0] = cvt_pk_bf16(kpa[ii][0], kpa[ii][1]);                           \
        w.u[1] = cvt_pk_bf16(kpa[ii][2], kpa[ii][3]);                           \
        w.u[2] = cvt_pk_bf16(kpb[ii][0], kpb[ii][1]);                           \
        w.u[3] = cvt_pk_bf16(kpb[ii][2], kpb[ii][3]);                           \
        *(bf16x8*)&Ksm[lteam][kr * 128 + ((dc16 ^ (kr & 7)) * 8)] = w.v;        \
      }                                                                         \
      {                                                                         \
        const int lteam = vq >> 3, vprb = vq & 7;                               \
        _Pragma("unroll")                                                       \
        for (int ii = 0; ii < 4; ++ii) {                                        \
          const int pr = vprb + ii * 8;                                         \
          _Pragma("unroll")                                                     \
          for (int jj = 0; jj < 4; ++jj) {                                      \
            const int row = vd + jj * 32;                                       \
            const unsigned pk = cvt_pk_bf16(vp[ii][jj][0], vp[ii][jj][1]);      \
            *(unsigned*)&Vsm[lteam][row * 64 + (((pr >> 2) ^ (row & 7)) * 8)    \
                                    + (pr & 3) * 2] = pk;                       \
          }                                                                     \
        }                                                                       \
      }                                                                         \
    }

  // ---- prologue: stage both teams' tile 0 ----
  STAGE_LOAD(0)
  STAGE_WRITE()
  __syncthreads();

  const int kvteam = team * h * 64;
  const int rowmax = q0 + wv * 32 + 31;

  for (int i = 0; i < h; ++i) {
    const int kv0 = kvteam + i * 64;
    const bool have_next = (i + 1 < h);

    // ---- issue next-tile loads NOW; latency hides under compute ----
    if (have_next) STAGE_LOAD(i + 1)
    __builtin_amdgcn_sched_barrier(0);   // pin load issue above compute

    if (kv0 <= rowmax) {   // wave has unmasked work in this tile
      // ---- swapped QK^T: S^T = mfma(K, Q); lane: S[q=lo][kv=nb*16+g*4+r] ----
      f32x4 s[2][4];
      #pragma unroll
      for (int mt = 0; mt < 2; ++mt)
        #pragma unroll
        for (int nb = 0; nb < 4; ++nb) s[mt][nb] = (f32x4){0.f, 0.f, 0.f, 0.f};

      __builtin_amdgcn_s_setprio(1);
      #pragma unroll
      for (int nb = 0; nb < 4; ++nb) {
        #pragma unroll
        for (int kb = 0; kb < 4; ++kb) {
          bf16x8 kf = *(const bf16x8*)&Ksm[team][(nb * 16 + lo) * 128 + (((kb * 4 + g) ^ lo7) * 8)];
          s[0][nb] = __builtin_amdgcn_mfma_f32_16x16x32_bf16(kf, qf[0][kb], s[0][nb], 0, 0, 0);
          s[1][nb] = __builtin_amdgcn_mfma_f32_16x16x32_bf16(kf, qf[1][kb], s[1][nb], 0, 0, 0);
        }
      }
      __builtin_amdgcn_s_setprio(0);

      // ---- causal mask ----
      if (kv0 + 63 > q0 + wv * 32) {
        #pragma unroll
        for (int mt = 0; mt < 2; ++mt) {
          const int qrow = q0 + wv * 32 + mt * 16 + lo;
          #pragma unroll
          for (int nb = 0; nb < 4; ++nb) {
            const int kvb = kv0 + nb * 16 + g * 4;
            #pragma unroll
            for (int r = 0; r < 4; ++r)
              if (kvb + r > qrow) s[mt][nb][r] = -1.0e30f;
          }
        }
      }

      // ---- online softmax (scalar per lane, defer-max) + P -> B-frags ----
      bf16x8 pfrag[2][2];
      #pragma unroll
      for (int mt = 0; mt < 2; ++mt) {
        float tm = s[mt][0][0];
        #pragma unroll
        for (int nb = 0; nb < 4; ++nb)
          #pragma unroll
          for (int r = 0; r < 4; ++r) tm = fmaxf(tm, s[mt][nb][r]);
        tm = fmaxf(tm, __shfl_xor(tm, 16));
        tm = fmaxf(tm, __shfl_xor(tm, 32));

        // T13: only rescale when the running max actually grew past THR
        if (!__all(tm <= m_st[mt] + DMTHR)) {
          const float mn = fmaxf(m_st[mt], tm);
          const float alpha = __builtin_amdgcn_exp2f((m_st[mt] - mn) * LOG2E);
          m_st[mt] = mn;
          l_st[mt] *= alpha;
          #pragma unroll
          for (int nd = 0; nd < 8; ++nd)
            #pragma unroll
            for (int r = 0; r < 4; ++r) o_acc[mt][nd][r] *= alpha;
        }

        float p[4][4];
        float ps = 0.0f;
        #pragma unroll
        for (int nb = 0; nb < 4; ++nb)
          #pragma unroll
          for (int r = 0; r < 4; ++r) {
            p[nb][r] = __builtin_amdgcn_exp2f((s[mt][nb][r] - m_st[mt]) * LOG2E);
            ps += p[nb][r];
          }
        ps += __shfl_xor(ps, 16);
        ps += __shfl_xor(ps, 32);
        l_st[mt] += ps;

        // pack P pairs via cvt_pk: pk[n1][n0][w] = kv pair (n1*32+n0*16+g*4+2w, +1)
        unsigned pk[2][2][2];
        #pragma unroll
        for (int n1 = 0; n1 < 2; ++n1)
          #pragma unroll
          for (int n0 = 0; n0 < 2; ++n0)
            #pragma unroll
            for (int w = 0; w < 2; ++w)
              pk[n1][n0][w] = cvt_pk_bf16(p[n1 * 2 + n0][2 * w], p[n1 * 2 + n0][2 * w + 1]);

        // butterfly: swap reg-bit n0 <-> lane-bit b1 (xor32), then rb <-> b0 (xor16)
        #pragma unroll
        for (int n1 = 0; n1 < 2; ++n1) {
          unsigned q2[2][2];
          #pragma unroll
          for (int w = 0; w < 2; ++w) {
            unsigned a = pk[n1][0][w], b = pk[n1][1][w];
            unsigned recv = __shfl_xor(b1 ? a : b, 32);
            unsigned r0 = b1 ? recv : a;
            unsigned r1 = b1 ? b : recv;
            unsigned recv2 = __shfl_xor(b0 ? r0 : r1, 16);
            q2[0][w] = b0 ? recv2 : r0;
            q2[1][w] = b0 ? r1 : recv2;
          }
          union { bf16x8 v; unsigned u[4]; } fb;
          fb.u[0] = q2[0][0]; fb.u[1] = q2[0][1]; fb.u[2] = q2[1][0]; fb.u[3] = q2[1][1];
          pfrag[mt][n1] = fb.v;   // B-frag: P^T[kv = n1*32 + g*8 + j][q = lo]
        }
      }

      // ---- PV: O^T += mfma(A=V^T, B=P^T) ----
      __builtin_amdgcn_s_setprio(1);
      #pragma unroll
      for (int kb2 = 0; kb2 < 2; ++kb2) {
        #pragma unroll
        for (int nd = 0; nd < 8; ++nd) {
          bf16x8 vf = *(const bf16x8*)&Vsm[team][(nd * 16 + lo) * 64 + (((kb2 * 4 + g) ^ lo7) * 8)];
          o_acc[0][nd] = __builtin_amdgcn_mfma_f32_16x16x32_bf16(vf, pfrag[0][kb2], o_acc[0][nd], 0, 0, 0);
          o_acc[1][nd] = __builtin_amdgcn_mfma_f32_16x16x32_bf16(vf, pfrag[1][kb2], o_acc[1][nd], 0, 0, 0);
        }
      }
      __builtin_amdgcn_s_setprio(0);
    }

    __syncthreads();   // barrier1: all waves done reading tile i

    // ---- write prefetched regs -> buffers (vmcnt drains here) ----
    if (have_next) {
      STAGE_WRITE()
      __syncthreads();   // barrier2: tile i+1 published
    }
  }

  // ---- merge kv-split halves: pair = (team0 wv, team1 wv), same q-rows ----
  // 16 KB f32 region per pair, carved from Ksm/Vsm (all LDS reads done).
  float* Opart = (wv < 2) ? (float*)&Ksm[wv][0] : (float*)&Vsm[wv - 2][0];

  if (team == 1) {
    #pragma unroll
    for (int mt = 0; mt < 2; ++mt) {
      #pragma unroll
      for (int nd = 0; nd < 8; ++nd)
        *(f32x4*)&Opart[(mt * 16 + lo) * 128 + nd * 16 + g * 4] = o_acc[mt][nd];
      if (g == 0) {
        MLsm[wv][0][mt][lo] = m_st[mt];
        MLsm[wv][1][mt][lo] = l_st[mt];
      }
    }
  }
  __syncthreads();

  if (team == 0) {
    #pragma unroll
    for (int mt = 0; mt < 2; ++mt) {
      const float mB = MLsm[wv][0][mt][lo];
      const float lB = MLsm[wv][1][mt][lo];
      const float m  = fmaxf(m_st[mt], mB);
      const float aA = __builtin_amdgcn_exp2f((m_st[mt] - m) * LOG2E);
      const float aB = __builtin_amdgcn_exp2f((mB - m) * LOG2E);
      const float l  = l_st[mt] * aA + lB * aB;
      const float inv = 1.0f / l;
      const int q = q0 + wv * 32 + mt * 16 + lo;
      #pragma unroll
      for (int nd = 0; nd < 8; ++nd) {
        f32x4 oB = *(const f32x4*)&Opart[(mt * 16 + lo) * 128 + nd * 16 + g * 4];
        f32x4 o;
        #pragma unroll
        for (int r = 0; r < 4; ++r)
          o[r] = (o_acc[mt][nd][r] * aA + oB[r] * aB) * inv;
        *(f32x4*)(Ob + (size_t)q * 128 + nd * 16 + g * 4) = o;
      }
    }
  }
}

extern "C" void kernel_launch(void* const* d_in, const int* in_sizes, int n_in,
                              void* d_out, int out_size, void* d_ws, size_t ws_size,
                              hipStream_t stream) {
  const float* Q = (const float*)d_in[0];
  const float* K = (const float*)d_in[1];
  const float* V = (const float*)d_in[2];
  float* O = (float*)d_out;
  attn_fwd<<<dim3(64, 16), 512, 0, stream>>>(Q, K, V, O);
}